// Round 11
// baseline (49.529 us; speedup 1.0000x reference)
//
#include <hip/hip_runtime.h>
#include <math.h>

#define B_ 512
#define I_ 512
#define O_ 512
#define BO_ (B_*O_)

// fast path (kanW): block = 64b x 64o x 16i, thread = 4b x 4o, ONE barrier
#define ZW 32                  // i-splits (grid = 8 ot x 8 bt x 32 iz = 2048)

// legacy kanZ fallback tiling
#define TB 64
#define TO 16
#define KI 16
#define ZN 8
#define NIZ (I_/ZN)
#define NCHZ (NIZ/KI)
#define LXS (TB + 4)

#define SQH    0.84932180028801904f   // sqrt(0.5*log2(e))
#define MN_   (-1.2023679775792928f)  // -(2 ln2) * NORM
#define NN_   (-0.86732507058407750f) // -NORM
#define BN_EPS (1e-5f)

#if defined(__has_builtin)
#if __has_builtin(__builtin_amdgcn_exp2f)
#define EXP2F(v) __builtin_amdgcn_exp2f(v)
#endif
#endif
#ifndef EXP2F
#define EXP2F(v) exp2f(v)
#endif

// ---------------------------------------------------------------------------
// K1: one-shot partial KAN sums. Block = 64b x 64o x 16i; thread = 4b x 4o.
// Stages raw params, derives {c,g,m,n} in-kernel (short live ranges, no
// spill), writes k-plane LDS layout (eval reads conflict-free: 16 lanes read
// contiguous 256B; x is broadcast). ONE __syncthreads per block. 2048 blocks
// = 8/CU = 32 waves/CU. fid&7 = o-tile = XCD owner (params/pY L2-local).
// ---------------------------------------------------------------------------
__global__ __launch_bounds__(256) void kanW(
    const float* __restrict__ x, const float* __restrict__ scale,
    const float* __restrict__ bias, const float* __restrict__ weight,
    float* __restrict__ pY)
{
    __shared__ float4 Lp[16][4][16];   // [i][k][o4] {c,g,m,n}   16 KB
    __shared__ float  Lx[16][64];      // [i][b]                  4 KB

    const int fid = blockIdx.x;
    const int ot  = fid & 7;               // XCD-owned o-tile (64 o)
    const int bt  = (fid >> 3) & 7;        // 8 b-tiles of 64
    const int iz  = fid >> 6;              // 0..31

    const int o0 = ot * 64;
    const int b0 = bt * 64;
    const int i0 = iz * 16;

    const int t   = threadIdx.x;
    const int oq  = t & 15;                // eval o-quad  (o = o0 + oq*4 + k)
    const int bq  = t >> 4;                // eval b-quad  (b = b0 + bq*4 + r)
    const int si  = t >> 4;                // staging i-row 0..15
    const int so4 = t & 15;                // staging o-quad
    const int lb  = t >> 2;                // x staging b 0..63
    const int lq  = t & 3;                 // x staging i-quarter

    // --- staging: global loads (short live ranges) -> derive -> LDS ---
    {
        const size_t g = (size_t)(i0 + si) * O_ + o0 + so4 * 4;
        const float4 s4 = *reinterpret_cast<const float4*>(&scale[g]);
        const float4 b4 = *reinterpret_cast<const float4*>(&bias[g]);
        const float4 w4 = *reinterpret_cast<const float4*>(&weight[g]);
        const float4 xv = *reinterpret_cast<const float4*>(
            &x[(size_t)(b0 + lb) * I_ + i0 + lq * 4]);

        {
            const float c = SQH * __builtin_amdgcn_rcpf(s4.x);
            Lp[si][0][so4] = make_float4(c, -b4.x * c, MN_ * w4.x, NN_ * w4.x);
        }
        {
            const float c = SQH * __builtin_amdgcn_rcpf(s4.y);
            Lp[si][1][so4] = make_float4(c, -b4.y * c, MN_ * w4.y, NN_ * w4.y);
        }
        {
            const float c = SQH * __builtin_amdgcn_rcpf(s4.z);
            Lp[si][2][so4] = make_float4(c, -b4.z * c, MN_ * w4.z, NN_ * w4.z);
        }
        {
            const float c = SQH * __builtin_amdgcn_rcpf(s4.w);
            Lp[si][3][so4] = make_float4(c, -b4.w * c, MN_ * w4.w, NN_ * w4.w);
        }
        Lx[lq * 4 + 0][lb] = xv.x;
        Lx[lq * 4 + 1][lb] = xv.y;
        Lx[lq * 4 + 2][lb] = xv.z;
        Lx[lq * 4 + 3][lb] = xv.w;
    }

    __syncthreads();                       // the only barrier

    float4 a0 = {0,0,0,0}, a1 = {0,0,0,0}, a2 = {0,0,0,0}, a3 = {0,0,0,0};

#define EVQ(xs, A)                                                           \
    {                                                                        \
        { const float h  = fmaf((xs), p0.x, p0.y);                           \
          const float un = -h * h;                                           \
          const float e  = EXP2F(un);                                        \
          const float gg = fmaf(un, p0.z, p0.w);                             \
          A.x = fmaf(gg, e, A.x); }                                          \
        { const float h  = fmaf((xs), p1.x, p1.y);                           \
          const float un = -h * h;                                           \
          const float e  = EXP2F(un);                                        \
          const float gg = fmaf(un, p1.z, p1.w);                             \
          A.y = fmaf(gg, e, A.y); }                                          \
        { const float h  = fmaf((xs), p2.x, p2.y);                           \
          const float un = -h * h;                                           \
          const float e  = EXP2F(un);                                        \
          const float gg = fmaf(un, p2.z, p2.w);                             \
          A.z = fmaf(gg, e, A.z); }                                          \
        { const float h  = fmaf((xs), p3.x, p3.y);                           \
          const float un = -h * h;                                           \
          const float e  = EXP2F(un);                                        \
          const float gg = fmaf(un, p3.z, p3.w);                             \
          A.w = fmaf(gg, e, A.w); }                                          \
    }

    #pragma unroll 4
    for (int ii = 0; ii < 16; ++ii) {
        const float4 p0 = Lp[ii][0][oq];   // lanes 0-15: contiguous 256B, free
        const float4 p1 = Lp[ii][1][oq];
        const float4 p2 = Lp[ii][2][oq];
        const float4 p3 = Lp[ii][3][oq];
        const float4 x4 = *reinterpret_cast<const float4*>(&Lx[ii][bq * 4]);
        EVQ(x4.x, a0);
        EVQ(x4.y, a1);
        EVQ(x4.z, a2);
        EVQ(x4.w, a3);
    }
#undef EVQ

    const size_t base = ((size_t)iz * B_ + b0 + bq * 4) * O_ + o0 + oq * 4;
    *reinterpret_cast<float4*>(&pY[base + 0 * O_]) = a0;
    *reinterpret_cast<float4*>(&pY[base + 1 * O_]) = a1;
    *reinterpret_cast<float4*>(&pY[base + 2 * O_]) = a2;
    *reinterpret_cast<float4*>(&pY[base + 3 * O_]) = a3;
}

// ---------------------------------------------------------------------------
// kanZ (proven R7 kernel) — fallback for small workspace (needs 8 MB).
// ---------------------------------------------------------------------------
__global__ __launch_bounds__(256) void kanZ(
    const float* __restrict__ x, const float* __restrict__ scale,
    const float* __restrict__ bias, const float* __restrict__ weight,
    float* __restrict__ pY)
{
    __shared__ float Lx[KI][LXS];
    __shared__ float Lp[KI][TO][4];

    const int fid = blockIdx.x;
    const int xcd = fid & 7;
    const int seq = fid >> 3;
    const int ot  = xcd * 4 + (seq & 3);
    const int by  = (seq >> 2) & 7;
    const int iz  = seq >> 5;

    const int o0 = ot * TO;
    const int b0 = by * TB;
    const int z0 = iz * NIZ;

    const int t   = threadIdx.x;
    const int to  = t & (TO - 1);
    const int tb4 = t >> 4;
    const int lb  = t >> 2;
    const int lq  = t & 3;
    const int li  = t >> 4;
    const int lo  = t & 15;

    float acc0 = 0.f, acc1 = 0.f, acc2 = 0.f, acc3 = 0.f;

    for (int ch = 0; ch < NCHZ; ++ch) {
        const int i0 = z0 + ch * KI;
        const float4 xv = *reinterpret_cast<const float4*>(
            &x[(size_t)(b0 + lb) * I_ + i0 + lq * 4]);
        const int pidx = (i0 + li) * O_ + o0 + lo;
        const float sc = scale[pidx];
        const float bi = bias[pidx];
        const float w  = weight[pidx];

        __syncthreads();
        Lx[lq * 4 + 0][lb] = xv.x;
        Lx[lq * 4 + 1][lb] = xv.y;
        Lx[lq * 4 + 2][lb] = xv.z;
        Lx[lq * 4 + 3][lb] = xv.w;
        const float c = SQH * __builtin_amdgcn_rcpf(sc);
        Lp[li][lo][0] = c;
        Lp[li][lo][1] = -bi * c;
        Lp[li][lo][2] = MN_ * w;
        Lp[li][lo][3] = NN_ * w;
        __syncthreads();

        #pragma unroll
        for (int ii = 0; ii < KI; ++ii) {
            const float4 p  = *reinterpret_cast<const float4*>(&Lp[ii][to][0]);
            const float4 x4 = *reinterpret_cast<const float4*>(&Lx[ii][tb4 * 4]);
            {
                const float h  = fmaf(x4.x, p.x, p.y);
                const float un = -h * h;
                const float e  = EXP2F(un);
                const float gg = fmaf(un, p.z, p.w);
                acc0 = fmaf(gg, e, acc0);
            }
            {
                const float h  = fmaf(x4.y, p.x, p.y);
                const float un = -h * h;
                const float e  = EXP2F(un);
                const float gg = fmaf(un, p.z, p.w);
                acc1 = fmaf(gg, e, acc1);
            }
            {
                const float h  = fmaf(x4.z, p.x, p.y);
                const float un = -h * h;
                const float e  = EXP2F(un);
                const float gg = fmaf(un, p.z, p.w);
                acc2 = fmaf(gg, e, acc2);
            }
            {
                const float h  = fmaf(x4.w, p.x, p.y);
                const float un = -h * h;
                const float e  = EXP2F(un);
                const float gg = fmaf(un, p.z, p.w);
                acc3 = fmaf(gg, e, acc3);
            }
        }
    }

    const size_t base = ((size_t)iz * B_ + b0 + tb4 * 4) * O_ + o0 + to;
    pY[base + 0 * O_] = acc0;
    pY[base + 1 * O_] = acc1;
    pY[base + 2 * O_] = acc2;
    pY[base + 3 * O_] = acc3;
}

// ---------------------------------------------------------------------------
// K2: fused NZ-partial combine + BatchNorm stats + apply. 128 blocks, 4 o's
// each; o<->XCD mapping matches the producer so pY reads hit the local L2.
// ---------------------------------------------------------------------------
template <int NZ>
__global__ __launch_bounds__(256) void comb_bn(
    const float* __restrict__ pY,
    const float* __restrict__ gamma, const float* __restrict__ beta,
    float* __restrict__ y)
{
    __shared__ float Ws[4][8];
    __shared__ float Ac[8];

    const int bid = blockIdx.x;                       // 0..127
    const int o4  = (bid & 7) * 64 + (bid >> 3) * 4;  // XCD k owns o [64k,64k+64)
    const int t   = threadIdx.x;

    float4 v[2];
    float sx = 0.f, sy = 0.f, sz = 0.f, sw = 0.f;
    float qx = 0.f, qy = 0.f, qz = 0.f, qw = 0.f;
    #pragma unroll
    for (int r = 0; r < 2; ++r) {
        const int b = t + 256 * r;
        const size_t base = (size_t)b * O_ + o4;
        float4 a = *reinterpret_cast<const float4*>(&pY[base]);
        #pragma unroll
        for (int z = 1; z < NZ; ++z) {
            const float4 p = *reinterpret_cast<const float4*>(&pY[(size_t)z * BO_ + base]);
            a.x += p.x; a.y += p.y; a.z += p.z; a.w += p.w;
        }
        v[r] = a;
        sx += a.x; sy += a.y; sz += a.z; sw += a.w;
        qx += a.x * a.x; qy += a.y * a.y; qz += a.z * a.z; qw += a.w * a.w;
    }

    #pragma unroll
    for (int m = 1; m < 64; m <<= 1) {
        sx += __shfl_xor(sx, m); sy += __shfl_xor(sy, m);
        sz += __shfl_xor(sz, m); sw += __shfl_xor(sw, m);
        qx += __shfl_xor(qx, m); qy += __shfl_xor(qy, m);
        qz += __shfl_xor(qz, m); qw += __shfl_xor(qw, m);
    }
    if ((t & 63) == 0) {
        const int wv = t >> 6;
        Ws[wv][0] = sx; Ws[wv][1] = sy; Ws[wv][2] = sz; Ws[wv][3] = sw;
        Ws[wv][4] = qx; Ws[wv][5] = qy; Ws[wv][6] = qz; Ws[wv][7] = qw;
    }
    __syncthreads();
    if (t < 4) {
        const float s  = Ws[0][t]     + Ws[1][t]     + Ws[2][t]     + Ws[3][t];
        const float q  = Ws[0][t + 4] + Ws[1][t + 4] + Ws[2][t + 4] + Ws[3][t + 4];
        const float mean = s * (1.0f / B_);
        const float var  = q * (1.0f / B_) - mean * mean;
        const float inv  = rsqrtf(var + BN_EPS);
        const float a = gamma[o4 + t] * inv;
        Ac[t]     = a;
        Ac[t + 4] = fmaf(-mean, a, beta[o4 + t]);
    }
    __syncthreads();

    const float4 a4 = *reinterpret_cast<const float4*>(&Ac[0]);
    const float4 c4 = *reinterpret_cast<const float4*>(&Ac[4]);
    #pragma unroll
    for (int r = 0; r < 2; ++r) {
        const int b = t + 256 * r;
        float4 o;
        o.x = fmaf(v[r].x, a4.x, c4.x);
        o.y = fmaf(v[r].y, a4.y, c4.y);
        o.z = fmaf(v[r].z, a4.z, c4.z);
        o.w = fmaf(v[r].w, a4.w, c4.w);
        *reinterpret_cast<float4*>(&y[(size_t)b * O_ + o4]) = o;
    }
}

// ---------------------------------------------------------------------------

extern "C" void kernel_launch(void* const* d_in, const int* in_sizes, int n_in,
                              void* d_out, int out_size, void* d_ws, size_t ws_size,
                              hipStream_t stream) {
    const float* x      = (const float*)d_in[0];
    const float* scale  = (const float*)d_in[1];
    const float* bias   = (const float*)d_in[2];
    const float* weight = (const float*)d_in[3];
    const float* gamma  = (const float*)d_in[4];
    const float* beta   = (const float*)d_in[5];
    float* out = (float*)d_out;

    const size_t pYW_b = (size_t)ZW * BO_ * sizeof(float);    // 32 MB
    const size_t pYZ_b = (size_t)ZN * BO_ * sizeof(float);    // 8 MB

    if (ws_size >= pYW_b) {
        float* pY = (float*)d_ws;
        kanW<<<8 * 8 * ZW, 256, 0, stream>>>(x, scale, bias, weight, pY);  // 2048 blocks
        comb_bn<ZW><<<O_ / 4, 256, 0, stream>>>(pY, gamma, beta, out);     // 128 blocks
    } else if (ws_size >= pYZ_b) {
        float* pY = (float*)d_ws;
        kanZ<<<32 * 8 * 8, 256, 0, stream>>>(x, scale, bias, weight, pY);
        comb_bn<ZN><<<O_ / 4, 256, 0, stream>>>(pY, gamma, beta, out);
    }
}

// Round 12
// 34.497 us; speedup vs baseline: 1.4357x; 1.4357x over previous
//
#include <hip/hip_runtime.h>
#include <math.h>

#define B_ 512
#define I_ 512
#define O_ 512
#define BO_ (B_*O_)

// fast path (kanV): block = 128b x 64o x 32i (2 chunks), thread = 8b x 4o
#define ZV 16                  // i-splits (grid = 4 bt x 8 ot x 16 iz = 512)

// legacy kanZ fallback tiling
#define TB 64
#define TO 16
#define KI 16
#define ZN 8
#define NIZ (I_/ZN)
#define NCHZ (NIZ/KI)
#define LXS (TB + 4)

#define SQH    0.84932180028801904f   // sqrt(0.5*log2(e))
#define MN_   (-1.2023679775792928f)  // -(2 ln2) * NORM
#define NN_   (-0.86732507058407750f) // -NORM
#define BN_EPS (1e-5f)

#if defined(__has_builtin)
#if __has_builtin(__builtin_amdgcn_exp2f)
#define EXP2F(v) __builtin_amdgcn_exp2f(v)
#endif
#endif
#ifndef EXP2F
#define EXP2F(v) exp2f(v)
#endif

// ---------------------------------------------------------------------------
// K1: partial KAN sums. Block = 128b x 64o x 32i; thread = 8b x 4o (32 evals
// per ii on 6 ds_read_b128 -> ~3 B/eval, conflict-free: param k-planes give
// 16 lanes contiguous 256B reads; x reads are 4-address broadcasts).
// kanZ's proven staging: global loads issued BEFORE the barrier, derive with
// short live ranges, 2 barriers per chunk, no launch-bounds cap (no spill).
// Grid 512 = 2 blocks/CU. fid&7 = o-tile = XCD owner (params/pY L2-local).
// ---------------------------------------------------------------------------
__global__ __launch_bounds__(256) void kanV(
    const float* __restrict__ x, const float* __restrict__ scale,
    const float* __restrict__ bias, const float* __restrict__ weight,
    float* __restrict__ pY)
{
    __shared__ float4 Lp[16][4][16];   // [i][k][o4] {c,g,m,n}   16 KB
    __shared__ float  Lx[16][128];     // [i][b]                   8 KB

    const int fid = blockIdx.x;
    const int ot  = fid & 7;               // XCD-owned o-tile (64 o)
    const int bt  = (fid >> 3) & 3;        // 4 b-tiles of 128
    const int iz  = fid >> 5;              // 0..15

    const int o0 = ot * 64;
    const int b0 = bt * 128;
    const int z0 = iz * 32;

    const int t   = threadIdx.x;
    const int oq  = t & 15;                // eval o-quad (o = o0 + oq*4 + k)
    const int bq  = t >> 4;                // eval b-octet (b = b0 + bq*8 + r)
    const int si  = t >> 4;                // param staging i-row 0..15
    const int so4 = t & 15;                // param staging o-quad
    const int lb  = t >> 1;                // x staging b 0..127
    const int lh  = t & 1;                 // x staging i-half (8 floats)

    float4 a[8];
    #pragma unroll
    for (int r = 0; r < 8; ++r) a[r] = make_float4(0.f, 0.f, 0.f, 0.f);

    for (int ch = 0; ch < 2; ++ch) {
        const int i0 = z0 + ch * 16;

        // issue global loads before the barrier so they overlap the wait
        const size_t g = (size_t)(i0 + si) * O_ + o0 + so4 * 4;
        const float4 s4 = *reinterpret_cast<const float4*>(&scale[g]);
        const float4 b4 = *reinterpret_cast<const float4*>(&bias[g]);
        const float4 w4 = *reinterpret_cast<const float4*>(&weight[g]);
        const size_t xg = (size_t)(b0 + lb) * I_ + i0 + lh * 8;
        const float4 xv0 = *reinterpret_cast<const float4*>(&x[xg]);
        const float4 xv1 = *reinterpret_cast<const float4*>(&x[xg + 4]);

        __syncthreads();               // previous chunk fully consumed

        {
            const float c = SQH * __builtin_amdgcn_rcpf(s4.x);
            Lp[si][0][so4] = make_float4(c, -b4.x * c, MN_ * w4.x, NN_ * w4.x);
        }
        {
            const float c = SQH * __builtin_amdgcn_rcpf(s4.y);
            Lp[si][1][so4] = make_float4(c, -b4.y * c, MN_ * w4.y, NN_ * w4.y);
        }
        {
            const float c = SQH * __builtin_amdgcn_rcpf(s4.z);
            Lp[si][2][so4] = make_float4(c, -b4.z * c, MN_ * w4.z, NN_ * w4.z);
        }
        {
            const float c = SQH * __builtin_amdgcn_rcpf(s4.w);
            Lp[si][3][so4] = make_float4(c, -b4.w * c, MN_ * w4.w, NN_ * w4.w);
        }
        Lx[lh * 8 + 0][lb] = xv0.x;
        Lx[lh * 8 + 1][lb] = xv0.y;
        Lx[lh * 8 + 2][lb] = xv0.z;
        Lx[lh * 8 + 3][lb] = xv0.w;
        Lx[lh * 8 + 4][lb] = xv1.x;
        Lx[lh * 8 + 5][lb] = xv1.y;
        Lx[lh * 8 + 6][lb] = xv1.z;
        Lx[lh * 8 + 7][lb] = xv1.w;

        __syncthreads();               // staging visible

#define EVQ(xs, A)                                                           \
    {                                                                        \
        { const float h  = fmaf((xs), p0.x, p0.y);                           \
          const float un = -h * h;                                           \
          const float e  = EXP2F(un);                                        \
          const float gg = fmaf(un, p0.z, p0.w);                             \
          A.x = fmaf(gg, e, A.x); }                                          \
        { const float h  = fmaf((xs), p1.x, p1.y);                           \
          const float un = -h * h;                                           \
          const float e  = EXP2F(un);                                        \
          const float gg = fmaf(un, p1.z, p1.w);                             \
          A.y = fmaf(gg, e, A.y); }                                          \
        { const float h  = fmaf((xs), p2.x, p2.y);                           \
          const float un = -h * h;                                           \
          const float e  = EXP2F(un);                                        \
          const float gg = fmaf(un, p2.z, p2.w);                             \
          A.z = fmaf(gg, e, A.z); }                                          \
        { const float h  = fmaf((xs), p3.x, p3.y);                           \
          const float un = -h * h;                                           \
          const float e  = EXP2F(un);                                        \
          const float gg = fmaf(un, p3.z, p3.w);                             \
          A.w = fmaf(gg, e, A.w); }                                          \
    }

        #pragma unroll 2
        for (int ii = 0; ii < 16; ++ii) {
            const float4 p0 = Lp[ii][0][oq];   // 16 lanes: contiguous 256B
            const float4 p1 = Lp[ii][1][oq];
            const float4 p2 = Lp[ii][2][oq];
            const float4 p3 = Lp[ii][3][oq];
            const float4 xA = *reinterpret_cast<const float4*>(&Lx[ii][bq * 8 + 0]);
            const float4 xB = *reinterpret_cast<const float4*>(&Lx[ii][bq * 8 + 4]);
            EVQ(xA.x, a[0]);
            EVQ(xA.y, a[1]);
            EVQ(xA.z, a[2]);
            EVQ(xA.w, a[3]);
            EVQ(xB.x, a[4]);
            EVQ(xB.y, a[5]);
            EVQ(xB.z, a[6]);
            EVQ(xB.w, a[7]);
        }
#undef EVQ
    }

    // store: a[r].k is o = o0 + oq*4 + k => contiguous float4 (coalesced 256B)
    #pragma unroll
    for (int r = 0; r < 8; ++r) {
        const size_t base = ((size_t)iz * B_ + b0 + bq * 8 + r) * O_ + o0 + oq * 4;
        *reinterpret_cast<float4*>(&pY[base]) = a[r];
    }
}

// ---------------------------------------------------------------------------
// kanZ (proven R7 kernel) — fallback for small workspace (needs 8 MB).
// ---------------------------------------------------------------------------
__global__ __launch_bounds__(256) void kanZ(
    const float* __restrict__ x, const float* __restrict__ scale,
    const float* __restrict__ bias, const float* __restrict__ weight,
    float* __restrict__ pY)
{
    __shared__ float Lx[KI][LXS];
    __shared__ float Lp[KI][TO][4];

    const int fid = blockIdx.x;
    const int xcd = fid & 7;
    const int seq = fid >> 3;
    const int ot  = xcd * 4 + (seq & 3);
    const int by  = (seq >> 2) & 7;
    const int iz  = seq >> 5;

    const int o0 = ot * TO;
    const int b0 = by * TB;
    const int z0 = iz * NIZ;

    const int t   = threadIdx.x;
    const int to  = t & (TO - 1);
    const int tb4 = t >> 4;
    const int lb  = t >> 2;
    const int lq  = t & 3;
    const int li  = t >> 4;
    const int lo  = t & 15;

    float acc0 = 0.f, acc1 = 0.f, acc2 = 0.f, acc3 = 0.f;

    for (int ch = 0; ch < NCHZ; ++ch) {
        const int i0 = z0 + ch * KI;
        const float4 xv = *reinterpret_cast<const float4*>(
            &x[(size_t)(b0 + lb) * I_ + i0 + lq * 4]);
        const int pidx = (i0 + li) * O_ + o0 + lo;
        const float sc = scale[pidx];
        const float bi = bias[pidx];
        const float w  = weight[pidx];

        __syncthreads();
        Lx[lq * 4 + 0][lb] = xv.x;
        Lx[lq * 4 + 1][lb] = xv.y;
        Lx[lq * 4 + 2][lb] = xv.z;
        Lx[lq * 4 + 3][lb] = xv.w;
        const float c = SQH * __builtin_amdgcn_rcpf(sc);
        Lp[li][lo][0] = c;
        Lp[li][lo][1] = -bi * c;
        Lp[li][lo][2] = MN_ * w;
        Lp[li][lo][3] = NN_ * w;
        __syncthreads();

        #pragma unroll
        for (int ii = 0; ii < KI; ++ii) {
            const float4 p  = *reinterpret_cast<const float4*>(&Lp[ii][to][0]);
            const float4 x4 = *reinterpret_cast<const float4*>(&Lx[ii][tb4 * 4]);
            {
                const float h  = fmaf(x4.x, p.x, p.y);
                const float un = -h * h;
                const float e  = EXP2F(un);
                const float gg = fmaf(un, p.z, p.w);
                acc0 = fmaf(gg, e, acc0);
            }
            {
                const float h  = fmaf(x4.y, p.x, p.y);
                const float un = -h * h;
                const float e  = EXP2F(un);
                const float gg = fmaf(un, p.z, p.w);
                acc1 = fmaf(gg, e, acc1);
            }
            {
                const float h  = fmaf(x4.z, p.x, p.y);
                const float un = -h * h;
                const float e  = EXP2F(un);
                const float gg = fmaf(un, p.z, p.w);
                acc2 = fmaf(gg, e, acc2);
            }
            {
                const float h  = fmaf(x4.w, p.x, p.y);
                const float un = -h * h;
                const float e  = EXP2F(un);
                const float gg = fmaf(un, p.z, p.w);
                acc3 = fmaf(gg, e, acc3);
            }
        }
    }

    const size_t base = ((size_t)iz * B_ + b0 + tb4 * 4) * O_ + o0 + to;
    pY[base + 0 * O_] = acc0;
    pY[base + 1 * O_] = acc1;
    pY[base + 2 * O_] = acc2;
    pY[base + 3 * O_] = acc3;
}

// ---------------------------------------------------------------------------
// K2: fused NZ-partial combine + BatchNorm stats + apply. 128 blocks, 4 o's
// each; o<->XCD mapping matches the producer so pY reads hit the local L2.
// ---------------------------------------------------------------------------
template <int NZ>
__global__ __launch_bounds__(256) void comb_bn(
    const float* __restrict__ pY,
    const float* __restrict__ gamma, const float* __restrict__ beta,
    float* __restrict__ y)
{
    __shared__ float Ws[4][8];
    __shared__ float Ac[8];

    const int bid = blockIdx.x;                       // 0..127
    const int o4  = (bid & 7) * 64 + (bid >> 3) * 4;  // XCD k owns o [64k,64k+64)
    const int t   = threadIdx.x;

    float4 v[2];
    float sx = 0.f, sy = 0.f, sz = 0.f, sw = 0.f;
    float qx = 0.f, qy = 0.f, qz = 0.f, qw = 0.f;
    #pragma unroll
    for (int r = 0; r < 2; ++r) {
        const int b = t + 256 * r;
        const size_t base = (size_t)b * O_ + o4;
        float4 a = *reinterpret_cast<const float4*>(&pY[base]);
        #pragma unroll
        for (int z = 1; z < NZ; ++z) {
            const float4 p = *reinterpret_cast<const float4*>(&pY[(size_t)z * BO_ + base]);
            a.x += p.x; a.y += p.y; a.z += p.z; a.w += p.w;
        }
        v[r] = a;
        sx += a.x; sy += a.y; sz += a.z; sw += a.w;
        qx += a.x * a.x; qy += a.y * a.y; qz += a.z * a.z; qw += a.w * a.w;
    }

    #pragma unroll
    for (int m = 1; m < 64; m <<= 1) {
        sx += __shfl_xor(sx, m); sy += __shfl_xor(sy, m);
        sz += __shfl_xor(sz, m); sw += __shfl_xor(sw, m);
        qx += __shfl_xor(qx, m); qy += __shfl_xor(qy, m);
        qz += __shfl_xor(qz, m); qw += __shfl_xor(qw, m);
    }
    if ((t & 63) == 0) {
        const int wv = t >> 6;
        Ws[wv][0] = sx; Ws[wv][1] = sy; Ws[wv][2] = sz; Ws[wv][3] = sw;
        Ws[wv][4] = qx; Ws[wv][5] = qy; Ws[wv][6] = qz; Ws[wv][7] = qw;
    }
    __syncthreads();
    if (t < 4) {
        const float s  = Ws[0][t]     + Ws[1][t]     + Ws[2][t]     + Ws[3][t];
        const float q  = Ws[0][t + 4] + Ws[1][t + 4] + Ws[2][t + 4] + Ws[3][t + 4];
        const float mean = s * (1.0f / B_);
        const float var  = q * (1.0f / B_) - mean * mean;
        const float inv  = rsqrtf(var + BN_EPS);
        const float a = gamma[o4 + t] * inv;
        Ac[t]     = a;
        Ac[t + 4] = fmaf(-mean, a, beta[o4 + t]);
    }
    __syncthreads();

    const float4 a4 = *reinterpret_cast<const float4*>(&Ac[0]);
    const float4 c4 = *reinterpret_cast<const float4*>(&Ac[4]);
    #pragma unroll
    for (int r = 0; r < 2; ++r) {
        const int b = t + 256 * r;
        float4 o;
        o.x = fmaf(v[r].x, a4.x, c4.x);
        o.y = fmaf(v[r].y, a4.y, c4.y);
        o.z = fmaf(v[r].z, a4.z, c4.z);
        o.w = fmaf(v[r].w, a4.w, c4.w);
        *reinterpret_cast<float4*>(&y[(size_t)b * O_ + o4]) = o;
    }
}

// ---------------------------------------------------------------------------

extern "C" void kernel_launch(void* const* d_in, const int* in_sizes, int n_in,
                              void* d_out, int out_size, void* d_ws, size_t ws_size,
                              hipStream_t stream) {
    const float* x      = (const float*)d_in[0];
    const float* scale  = (const float*)d_in[1];
    const float* bias   = (const float*)d_in[2];
    const float* weight = (const float*)d_in[3];
    const float* gamma  = (const float*)d_in[4];
    const float* beta   = (const float*)d_in[5];
    float* out = (float*)d_out;

    const size_t pYV_b = (size_t)ZV * BO_ * sizeof(float);    // 16 MB
    const size_t pYZ_b = (size_t)ZN * BO_ * sizeof(float);    // 8 MB

    if (ws_size >= pYV_b) {
        float* pY = (float*)d_ws;
        kanV<<<8 * 4 * ZV, 256, 0, stream>>>(x, scale, bias, weight, pY);  // 512 blocks
        comb_bn<ZV><<<O_ / 4, 256, 0, stream>>>(pY, gamma, beta, out);     // 128 blocks
    } else if (ws_size >= pYZ_b) {
        float* pY = (float*)d_ws;
        kanZ<<<32 * 8 * 8, 256, 0, stream>>>(x, scale, bias, weight, pY);
        comb_bn<ZN><<<O_ / 4, 256, 0, stream>>>(pY, gamma, beta, out);
    }
}